// Round 2
// baseline (13.591 us; speedup 1.0000x reference)
//
#include <hip/hip_runtime.h>
#include <hip/hip_bf16.h>

// Embedding gather disguised as one-hot matmul:
//   out[token, h] = W[h, src[token]] + bias[h]
// Dtypes (proven by npz sizes in round-1 timing block):
//   src  [B*S=4096]      int32   (int64 in JAX, canonicalized -> const int*)
//   W    [H=128, V=32000] float32 (row-major; token gathers a COLUMN, stride V)
//   bias [128]           float32
//   out  [4096, 128]     float32

#define VOCAB 32000
#define HDIM  128
#define NTOK  (16 * 256)   // B*S
#define NELEM (NTOK * HDIM)

__global__ __launch_bounds__(256) void embed_gather_kernel(
    const int* __restrict__ src,
    const float* __restrict__ W,
    const float* __restrict__ bias,
    float* __restrict__ out)
{
    const int tid = blockIdx.x * 256 + threadIdx.x;  // one thread per output element
    if (tid >= NELEM) return;

    const int token = tid >> 7;    // tid / HDIM
    const int h     = tid & 127;   // tid % HDIM

    const int idx = src[token];    // uniform within each 128-thread token group

    // Column gather: stride-V f32 access; W (16.4 MB) is L2/L3-resident.
    const float w = W[(size_t)h * VOCAB + idx];
    const float b = bias[h];

    out[tid] = w + b;              // fully coalesced f32 store
}

extern "C" void kernel_launch(void* const* d_in, const int* in_sizes, int n_in,
                              void* d_out, int out_size, void* d_ws, size_t ws_size,
                              hipStream_t stream) {
    const int*   src  = (const int*)d_in[0];
    const float* W    = (const float*)d_in[1];
    const float* bias = (const float*)d_in[2];
    float*       out  = (float*)d_out;

    const int threads = 256;
    const int blocks  = (NELEM + threads - 1) / threads;  // 2048
    embed_gather_kernel<<<blocks, threads, 0, stream>>>(src, W, bias, out);
}

// Round 3
// 10.566 us; speedup vs baseline: 1.2863x; 1.2863x over previous
//
#include <hip/hip_runtime.h>
#include <hip/hip_bf16.h>

// Embedding gather disguised as one-hot matmul:
//   out[token, h] = W[h, src[token]] + bias[h]
//   src [4096] int32, W [128, 32000] f32 row-major, bias [128] f32, out [4096,128] f32.
//
// Inverted (scatter) formulation: 4096 random indices touch ~87% of W's 64B
// lines, so a fully-coalesced read of ALL of W (16.4 MB) costs barely more
// bytes than the scattered gather (~33.5 MB line traffic at 4B/64B efficiency)
// and runs on the fast path. Each block owns a 32-column stripe of W,
// stages it in LDS, finds the tokens that map into its stripe, and writes
// their embedding rows as contiguous 512B stores.

#define VOCAB 32000
#define HDIM  128
#define NTOK  (16 * 256)       // B*S = 4096
#define VPB   32               // vocab columns per block
#define NBLK  (VOCAB / VPB)    // 1000

__global__ __launch_bounds__(256) void embed_scatter_kernel(
    const int* __restrict__ src,
    const float* __restrict__ W,
    const float* __restrict__ bias,
    float* __restrict__ out)
{
    __shared__ float tile[HDIM][VPB + 1];  // +1 pad: stride 33 words -> conflict-free both axes
    __shared__ int   list[NTOK];           // worst-case all tokens in one stripe
    __shared__ int   nmatch;

    const int t  = threadIdx.x;
    const int v0 = blockIdx.x * VPB;

    if (t == 0) nmatch = 0;

    // (a) stage W stripe: lanes 0..31 read consecutive v -> 128B segments per row
    const int vi = t & 31;
    for (int h = t >> 5; h < HDIM; h += 8)
        tile[h][vi] = W[(size_t)h * VOCAB + v0 + vi];
    __syncthreads();   // also publishes nmatch = 0

    // (b) scan src (16KB, L2-broadcast across blocks), collect matches
    for (int i = t; i < NTOK; i += 256) {
        const unsigned d = (unsigned)(src[i] - v0);
        if (d < VPB) {
            const int slot = atomicAdd(&nmatch, 1);   // LDS atomic
            list[slot] = (i << 5) | (int)d;           // pack token(12b) | col(5b)
        }
    }
    __syncthreads();

    // (c) write matched embedding rows: 2 tokens per 256-thread pass,
    //     threads 0..127 cover h -> contiguous 512B store per token
    const int   n  = nmatch;
    const int   h  = t & 127;
    const float bb = bias[h];
    for (int j = t >> 7; j < n; j += 2) {
        const int e   = list[j];
        const int tok = e >> 5;
        const int col = e & 31;
        out[(size_t)tok * HDIM + h] = tile[h][col] + bb;
    }
}

extern "C" void kernel_launch(void* const* d_in, const int* in_sizes, int n_in,
                              void* d_out, int out_size, void* d_ws, size_t ws_size,
                              hipStream_t stream) {
    const int*   src  = (const int*)d_in[0];
    const float* W    = (const float*)d_in[1];
    const float* bias = (const float*)d_in[2];
    float*       out  = (float*)d_out;

    embed_scatter_kernel<<<NBLK, 256, 0, stream>>>(src, W, bias, out);
}

// Round 4
// 9.874 us; speedup vs baseline: 1.3765x; 1.0701x over previous
//
#include <hip/hip_runtime.h>
#include <hip/hip_bf16.h>

// Embedding gather disguised as one-hot matmul:
//   out[token, h] = W[h, src[token]] + bias[h]
//   src [4096] int32, W [128, 32000] f32 row-major, bias [128] f32, out [4096,128] f32.
//
// Inverted (scatter) formulation, now fully vectorized:
//  - each block owns a 32-column stripe of W, stages it [128x32] in LDS via
//    float4 loads (16B/lane), scans src via int4, and writes each matching
//    token's 512B embedding row via float4 stores.
//  - round-3 lesson: the 10.6us was VMEM-instruction-issue-bound (32 scalar
//    loads/thread); this cuts VMEM ~3x and widens every global access to 16B.

#define VOCAB  32000
#define HDIM   128
#define NTOK   (16 * 256)       // B*S = 4096
#define VPB    32               // vocab columns per block
#define NBLK   (VOCAB / VPB)    // 1000
#define STRIDE 33               // LDS row stride (words): odd -> conflict-free column reads

__global__ __launch_bounds__(256) void embed_scatter_kernel(
    const int* __restrict__ src,
    const float* __restrict__ W,
    const float* __restrict__ bias,
    float* __restrict__ out)
{
    __shared__ float tile[HDIM * STRIDE];  // 16.9 KB
    __shared__ int   list[NTOK];           // 16 KB, worst-case capacity
    __shared__ int   nmatch;

    const int t  = threadIdx.x;
    const int v0 = blockIdx.x * VPB;

    if (t == 0) nmatch = 0;
    __syncthreads();  // publish nmatch=0 before any LDS atomic

    // (a) stage W stripe: float4 loads, 8 float4 per row, 32 rows/pass, 4 passes
    {
        const int c4 = t & 7;        // float4 slot within row
        const int h0 = t >> 3;       // 0..31
        for (int h = h0; h < HDIM; h += 32) {
            const float4 v = *(const float4*)(W + (size_t)h * VOCAB + v0 + c4 * 4);
            float* dst = &tile[h * STRIDE + c4 * 4];
            dst[0] = v.x; dst[1] = v.y; dst[2] = v.z; dst[3] = v.w;  // dword writes: stride-33, conflict-free
        }
    }

    // (b) scan src via int4 (1024 int4 total, 256 threads -> 4 iterations)
    {
        const int4* src4 = (const int4*)src;
        for (int i = t; i < NTOK / 4; i += 256) {
            const int4 s = src4[i];
            const int base = i << 2;
            unsigned d;
            d = (unsigned)(s.x - v0); if (d < VPB) list[atomicAdd(&nmatch, 1)] = ((base + 0) << 5) | (int)d;
            d = (unsigned)(s.y - v0); if (d < VPB) list[atomicAdd(&nmatch, 1)] = ((base + 1) << 5) | (int)d;
            d = (unsigned)(s.z - v0); if (d < VPB) list[atomicAdd(&nmatch, 1)] = ((base + 2) << 5) | (int)d;
            d = (unsigned)(s.w - v0); if (d < VPB) list[atomicAdd(&nmatch, 1)] = ((base + 3) << 5) | (int)d;
        }
    }
    __syncthreads();

    // (c) write matched rows: 32 threads per token (float4 over h), 8 tokens/pass
    const int    n      = nmatch;
    const int    lane32 = t & 31;
    const int    h0     = lane32 * 4;
    const float4 bb     = ((const float4*)bias)[lane32];
    for (int j = t >> 5; j < n; j += 8) {
        const int e   = list[j];
        const int tok = e >> 5;
        const int col = e & 31;
        float4 r;
        r.x = tile[(h0 + 0) * STRIDE + col] + bb.x;  // column read: stride-33 -> conflict-free
        r.y = tile[(h0 + 1) * STRIDE + col] + bb.y;
        r.z = tile[(h0 + 2) * STRIDE + col] + bb.z;
        r.w = tile[(h0 + 3) * STRIDE + col] + bb.w;
        *(float4*)(out + (size_t)tok * HDIM + h0) = r;  // coalesced 512B per token
    }
}

extern "C" void kernel_launch(void* const* d_in, const int* in_sizes, int n_in,
                              void* d_out, int out_size, void* d_ws, size_t ws_size,
                              hipStream_t stream) {
    const int*   src  = (const int*)d_in[0];
    const float* W    = (const float*)d_in[1];
    const float* bias = (const float*)d_in[2];
    float*       out  = (float*)d_out;

    embed_scatter_kernel<<<NBLK, 256, 0, stream>>>(src, W, bias, out);
}

// Round 5
// 9.863 us; speedup vs baseline: 1.3780x; 1.0011x over previous
//
#include <hip/hip_runtime.h>
#include <hip/hip_bf16.h>

// Embedding gather disguised as one-hot matmul:
//   out[token, h] = W[h, src[token]] + bias[h]
//   src [4096] int32, W [128, 32000] f32 row-major, bias [128] f32, out [4096,128] f32.
//
// Inverted (scatter) formulation, round 5: latency-overlapped single-barrier.
//  - src int4 loads issued FIRST, W float4 loads second: vmcnt FIFO semantics
//    let the src scan run while W loads are still in flight.
//  - ballot-compaction into per-wave match lists (no LDS atomics, no counter
//    init, no first barrier). ONE __syncthreads total.
//  - phase c: 64 threads/token, float2 over h -> LDS lane stride 66 words
//    == 2 (mod 32): 2-way aliasing = free (m136). 512B coalesced stores.

#define VOCAB  32000
#define HDIM   128
#define NTOK   (16 * 256)       // B*S = 4096
#define VPB    32               // vocab columns per block
#define NBLK   (VOCAB / VPB)    // 1000
#define STRIDE 33               // LDS row stride in words

__global__ __launch_bounds__(256) void embed_scatter_kernel(
    const int* __restrict__ src,
    const float* __restrict__ W,
    const float* __restrict__ bias,
    float* __restrict__ out)
{
    __shared__ float tile[HDIM * STRIDE];   // 16.9 KB
    __shared__ int   list[NTOK];            // 16 KB: wave w owns [w*1024, w*1024+1024)
    __shared__ int   counts[4];

    const int t    = threadIdx.x;
    const int lane = t & 63;
    const int wav  = t >> 6;
    const int v0   = blockIdx.x * VPB;

    // ---- issue src loads FIRST (consumed earliest) ----
    const int4* src4 = (const int4*)src;
    int4 sv[4];
#pragma unroll
    for (int it = 0; it < 4; ++it) sv[it] = src4[t + (it << 8)];

    // ---- issue W loads second (consumed last; stay in flight during scan) ----
    const int c4 = t & 7;        // float4 slot within stripe row
    const int hh = t >> 3;       // 0..31
    float4 wv[4];
#pragma unroll
    for (int k = 0; k < 4; ++k)
        wv[k] = *(const float4*)(W + (size_t)(hh + (k << 5)) * VOCAB + v0 + (c4 << 2));

    // bias (tiny, L2-resident)
    const float2 bb = ((const float2*)bias)[lane];

    // ---- scan: ballot-compact matches into this wave's list region ----
    int cnt = 0;
    const unsigned long long ltmask = (1ull << lane) - 1ull;
    int* mylist = list + (wav << 10);
#pragma unroll
    for (int it = 0; it < 4; ++it) {
        const int base = (t + (it << 8)) << 2;   // first token id of this int4
        const int vals[4] = {sv[it].x, sv[it].y, sv[it].z, sv[it].w};
#pragma unroll
        for (int e = 0; e < 4; ++e) {
            const unsigned d = (unsigned)(vals[e] - v0);
            const bool pred = d < VPB;
            const unsigned long long mask = __ballot(pred);
            if (mask) {                           // wave-uniform skip (matches are rare)
                if (pred)
                    mylist[cnt + (int)__popcll(mask & ltmask)] = ((base + e) << 5) | (int)d;
                cnt += (int)__popcll(mask);
            }
        }
    }
    if (lane == 0) counts[wav] = cnt;

    // ---- store W tile (vmcnt drains here, AFTER the scan) ----
#pragma unroll
    for (int k = 0; k < 4; ++k) {
        float* dst = &tile[(hh + (k << 5)) * STRIDE + (c4 << 2)];
        dst[0] = wv[k].x; dst[1] = wv[k].y; dst[2] = wv[k].z; dst[3] = wv[k].w;
    }

    __syncthreads();   // the only barrier

    // ---- phase c: one wave per token, float2 over h ----
    const int h0 = lane << 1;
    for (int w = 0; w < 4; ++w) {
        const int  n  = counts[w];
        const int* lw = list + (w << 10);
        for (int j = wav; j < n; j += 4) {
            const int e   = lw[j];
            const int tok = e >> 5;
            const int col = e & 31;
            float2 r;
            r.x = tile[(h0 + 0) * STRIDE + col] + bb.x;  // lane stride 66 = 2 mod 32: free
            r.y = tile[(h0 + 1) * STRIDE + col] + bb.y;
            *(float2*)(out + (size_t)tok * HDIM + h0) = r;  // 512B coalesced per token
        }
    }
}

extern "C" void kernel_launch(void* const* d_in, const int* in_sizes, int n_in,
                              void* d_out, int out_size, void* d_ws, size_t ws_size,
                              hipStream_t stream) {
    const int*   src  = (const int*)d_in[0];
    const float* W    = (const float*)d_in[1];
    const float* bias = (const float*)d_in[2];
    float*       out  = (float*)d_out;

    embed_scatter_kernel<<<NBLK, 256, 0, stream>>>(src, W, bias, out);
}